// Round 2
// baseline (4880.989 us; speedup 1.0000x reference)
//
#include <hip/hip_runtime.h>
#include <stdint.h>

typedef unsigned long long u64;

#define NIMG 8
#define CIN 512
#define COUT 512
#define NPOS 4096            // 64*64
#define NSC 36864            // 9*64*64
#define PRE_TOPN 3000
#define POST_TOPN 300
#define NWORDS 47            // ceil(3000/64)
#define MSTRIDE 48           // padded words per mask row

__constant__ double dANC[9][4] = {
    {-83.0, -39.0, 100.0, 56.0},   {-175.0, -87.0, 192.0, 104.0},
    {-359.0, -183.0, 376.0, 200.0},{-55.0, -55.0, 72.0, 72.0},
    {-119.0, -119.0, 136.0, 136.0},{-247.0, -247.0, 264.0, 264.0},
    {-35.0, -79.0, 52.0, 96.0},    {-79.0, -167.0, 96.0, 184.0},
    {-167.0, -343.0, 184.0, 360.0}};

// ---------------- W transpose: W_conv [512oc][512ci*3*3] -> Wt [4608k][512oc]
__global__ __launch_bounds__(256) void transpose_wconv(const float* __restrict__ W,
                                                       float* __restrict__ Wt) {
    __shared__ float t[32][33];
    int k0 = blockIdx.x * 32;
    int o0 = blockIdx.y * 32;
    int tid = threadIdx.x;
    for (int idx = tid; idx < 1024; idx += 256) {
        int r = idx >> 5, c = idx & 31;
        t[r][c] = W[(size_t)(o0 + r) * 4608 + k0 + c];
    }
    __syncthreads();
    for (int idx = tid; idx < 1024; idx += 256) {
        int r = idx >> 5, c = idx & 31;
        Wt[(size_t)(k0 + r) * 512 + o0 + c] = t[c][r];
    }
}

// ---------------- heads W: Wh [512k][64o]  (o<36: W_reg, 36..53: W_cls, rest 0)
__global__ __launch_bounds__(256) void build_wheads(const float* __restrict__ Wreg,
                                                    const float* __restrict__ Wcls,
                                                    float* __restrict__ Wh) {
    int g = blockIdx.x * 256 + threadIdx.x;
    if (g >= 512 * 64) return;
    int k = g >> 6, o = g & 63;
    float v = 0.f;
    if (o < 36) v = Wreg[o * 512 + k];
    else if (o < 54) v = Wcls[(o - 36) * 512 + k];
    Wh[g] = v;
}

// ---------------- conv 3x3 SAME, fp64 accumulate, 64oc x 64pos(one row) tile
__global__ __launch_bounds__(256) void conv_kernel(const float* __restrict__ X,
                                                   const float* __restrict__ Wt,
                                                   const float* __restrict__ bconv,
                                                   double* __restrict__ convb,
                                                   int img_base) {
    const int tid = threadIdx.x;
    const int oc0 = blockIdx.x * 64;
    const int y = blockIdx.y;
    const int imgL = blockIdx.z;
    const int img_g = img_base + imgL;
    const int x_l = (tid & 15) * 4;
    const int oc_l = (tid >> 4) * 4;

    __shared__ float Wl[144][64];     // [16ci*9tap][64oc]
    __shared__ float Bx[16][3][68];   // [ci][row y-1..y+1][x(-1..64) pad]

    double acc[4][4];
#pragma unroll
    for (int i = 0; i < 4; ++i)
#pragma unroll
        for (int j = 0; j < 4; ++j) acc[i][j] = 0.0;

    for (int cc = 0; cc < CIN; cc += 16) {
        __syncthreads();
        for (int idx = tid; idx < 16 * 3 * 68; idx += 256) {
            int c_l = idx / 204;
            int rem = idx - c_l * 204;
            int r = rem / 68;
            int xx = rem - r * 68;
            int yy = y + r - 1;
            int xg = xx - 1;
            float v = 0.f;
            if (xx < 66 && (unsigned)yy < 64u && (unsigned)xg < 64u)
                v = X[(((size_t)img_g * CIN + cc + c_l) * 64 + yy) * 64 + xg];
            Bx[c_l][r][xx] = v;
        }
        for (int idx = tid; idx < 144 * 64; idx += 256) {
            int kl = idx >> 6, ol = idx & 63;
            Wl[kl][ol] = Wt[(size_t)(cc * 9 + kl) * 512 + oc0 + ol];
        }
        __syncthreads();
#pragma unroll 2
        for (int c_l = 0; c_l < 16; ++c_l) {
#pragma unroll
            for (int ty = 0; ty < 3; ++ty) {
                const float4 xa = *(const float4*)&Bx[c_l][ty][x_l];
                const float2 xb = *(const float2*)&Bx[c_l][ty][x_l + 4];
                double xv[6] = {(double)xa.x, (double)xa.y, (double)xa.z,
                                (double)xa.w, (double)xb.x, (double)xb.y};
#pragma unroll
                for (int tx = 0; tx < 3; ++tx) {
                    const float4 wv = *(const float4*)&Wl[c_l * 9 + ty * 3 + tx][oc_l];
                    double wr[4] = {(double)wv.x, (double)wv.y, (double)wv.z, (double)wv.w};
#pragma unroll
                    for (int i = 0; i < 4; ++i)
#pragma unroll
                        for (int j = 0; j < 4; ++j)
                            acc[i][j] = fma(wr[i], xv[j + tx], acc[i][j]);
                }
            }
        }
    }
#pragma unroll
    for (int i = 0; i < 4; ++i) {
        int oc = oc0 + oc_l + i;
        double b = (double)bconv[oc];
        double4 st;
        st.x = acc[i][0] + b; st.y = acc[i][1] + b;
        st.z = acc[i][2] + b; st.w = acc[i][3] + b;
        *(double4*)&convb[((size_t)imgL * COUT + oc) * NPOS + y * 64 + x_l] = st;
    }
}

// ---------------- heads: reg(36)+cls(18) fp64 GEMM + softmax + decode + clip
__global__ __launch_bounds__(256) void heads_kernel(const double* __restrict__ convb,
                                                    const float* __restrict__ Wh,
                                                    const float* __restrict__ breg,
                                                    const float* __restrict__ bcls,
                                                    const float* __restrict__ im_size,
                                                    float* __restrict__ out_scores,
                                                    float4* __restrict__ out_props,
                                                    double* __restrict__ dscores,
                                                    double4* __restrict__ dprops,
                                                    int img_base) {
    const int tid = threadIdx.x;
    const int y = blockIdx.x;
    const int imgL = blockIdx.y;
    const int img_g = img_base + imgL;

    __shared__ double cl[64][64];  // conv chunk [k][p]; later reused as headbuf[o][p]
    __shared__ float wl[64][64];   // heads W chunk [k][o]

    const int o = tid & 63;
    const int g = tid >> 6;
    double acc[16];
#pragma unroll
    for (int j = 0; j < 16; ++j) acc[j] = 0.0;

    for (int k0 = 0; k0 < CIN; k0 += 64) {
        __syncthreads();
        for (int idx = tid; idx < 4096; idx += 256) {
            int kl = idx >> 6, p = idx & 63;
            cl[kl][p] = convb[((size_t)imgL * COUT + k0 + kl) * NPOS + y * 64 + p];
        }
        for (int idx = tid; idx < 4096; idx += 256) {
            wl[idx >> 6][idx & 63] = Wh[(k0 + (idx >> 6)) * 64 + (idx & 63)];
        }
        __syncthreads();
        const bool ru = (o >= 36);
        for (int kl = 0; kl < 64; ++kl) {
            double w = (double)wl[kl][o];
#pragma unroll
            for (int j = 0; j < 16; ++j) {
                double v = cl[kl][g * 16 + j];
                if (ru) v = fmax(v, 0.0);
                acc[j] = fma(w, v, acc[j]);
            }
        }
    }
    __syncthreads();
    double bias = (o < 36) ? (double)breg[o] : (o < 54 ? (double)bcls[o - 36] : 0.0);
#pragma unroll
    for (int j = 0; j < 16; ++j) cl[o][g * 16 + j] = acc[j] + bias;
    __syncthreads();

    const double im_h = (double)im_size[img_g * 2 + 0];
    const double im_w = (double)im_size[img_g * 2 + 1];
    const double xmax = im_w - 1.0, ymax = im_h - 1.0;

    for (int t = tid; t < 576; t += 256) {
        int p = t / 9;
        int a = t - p * 9;
        double dx = cl[a * 4 + 0][p], dy = cl[a * 4 + 1][p];
        double dw = cl[a * 4 + 2][p], dh = cl[a * 4 + 3][p];
        double c0 = cl[36 + a][p], c1 = cl[45 + a][p];
        double mm = fmax(c0, c1);
        double e0 = exp(c0 - mm), e1 = exp(c1 - mm);
        double sc = e0 / (e0 + e1);

        double sx = (double)p * 16.0, sy = (double)y * 16.0;
        double a0 = dANC[a][0] + sx, a1 = dANC[a][1] + sy;
        double a2 = dANC[a][2] + sx, a3 = dANC[a][3] + sy;
        double w_ = a2 - a0 + 1.0, h_ = a3 - a1 + 1.0;
        double cx = a0 + 0.5 * w_, cy = a1 + 0.5 * h_;
        double pcx = dx * cx, pcy = dy * cy;
        double pw = exp(dw) * w_, ph = exp(dh) * h_;
        double x1 = pcx - 0.5 * pw, y1 = pcy - 0.5 * ph;
        double x2 = pcx + 0.5 * pw, y2 = pcy + 0.5 * ph;
        x1 = fmin(fmax(x1, 0.0), xmax);
        y1 = fmin(fmax(y1, 0.0), ymax);
        x2 = fmin(fmax(x2, 0.0), xmax);
        y2 = fmin(fmax(y2, 0.0), ymax);

        int pp = y * 64 + p;
        size_t si = (size_t)img_g * NSC + (size_t)a * NPOS + pp;   // anchor-major
        size_t pi = (size_t)img_g * NSC + (size_t)pp * 9 + a;      // position-major
        out_scores[si] = (float)sc;
        dscores[si] = sc;
        double4 db; db.x = x1; db.y = y1; db.z = x2; db.w = y2;
        dprops[pi] = db;
        out_props[pi] = make_float4((float)x1, (float)y1, (float)x2, (float)y2);
    }
}

// ---------------- exact 3000th-largest score bit pattern (u64 radix select)
__global__ __launch_bounds__(256) void topk_select(const double* __restrict__ dscores,
                                                   u64* __restrict__ Tsel) {
    const int img = blockIdx.x;
    const int tid = threadIdx.x;
    const u64* sb = (const u64*)(dscores + (size_t)img * NSC);
    __shared__ uint32_t hist[256];
    __shared__ u64 s_prefix;
    __shared__ uint32_t s_rem;
    if (tid == 0) { s_prefix = 0ull; s_rem = PRE_TOPN; }
    for (int pass = 0; pass < 8; ++pass) {
        int shift = 56 - pass * 8;
        hist[tid] = 0;
        __syncthreads();
        u64 pmask = pass ? (~0ull << (shift + 8)) : 0ull;
        u64 pref = s_prefix;
        for (int i = tid; i < NSC; i += 256) {
            u64 v = sb[i];
            if ((v & pmask) == pref) atomicAdd(&hist[(uint32_t)(v >> shift) & 0xFFu], 1u);
        }
        __syncthreads();
        if (tid == 0) {
            uint32_t rem = s_rem, cum = 0;
            int b = 255;
            for (; b > 0; --b) {
                if (cum + hist[b] >= rem) break;
                cum += hist[b];
            }
            s_prefix = pref | ((u64)(uint32_t)b << shift);
            s_rem = rem - cum;
        }
        __syncthreads();
    }
    if (tid == 0) Tsel[img] = s_prefix;
}

// ---------------- compact >=T, exact bitonic sort desc by (score, -idx), gather
__global__ __launch_bounds__(1024) void sort_gather(const double* __restrict__ dscores,
                                                    const double4* __restrict__ dprops,
                                                    const u64* __restrict__ Tsel,
                                                    double4* __restrict__ dboxes) {
    const int img = blockIdx.x;
    const int tid = threadIdx.x;
    __shared__ u64 skey[4096];
    __shared__ unsigned short sidx[4096];
    __shared__ int cnt;
    if (tid == 0) cnt = 0;
    for (int i = tid; i < 4096; i += 1024) { skey[i] = 0ull; sidx[i] = 0xFFFF; }
    __syncthreads();
    const u64 T = Tsel[img];
    const u64* sb = (const u64*)(dscores + (size_t)img * NSC);
    for (int i = tid; i < NSC; i += 1024) {
        u64 v = sb[i];
        if (v >= T) {
            int p = atomicAdd(&cnt, 1);
            if (p < 4096) { skey[p] = v; sidx[p] = (unsigned short)i; }
        }
    }
    __syncthreads();
    for (int k = 2; k <= 4096; k <<= 1) {
        for (int j = k >> 1; j > 0; j >>= 1) {
            for (int i = tid; i < 4096; i += 1024) {
                int ixj = i ^ j;
                if (ixj > i) {
                    u64 ka = skey[i], kb = skey[ixj];
                    unsigned short ia = sidx[i], ib = sidx[ixj];
                    // "a ranks after b" in descending-(score, asc idx) order
                    bool aw = (ka < kb) || (ka == kb && ia > ib);
                    bool up = (i & k) == 0;
                    if (up ? aw : !aw) {
                        skey[i] = kb; skey[ixj] = ka;
                        sidx[i] = ib; sidx[ixj] = ia;
                    }
                }
            }
            __syncthreads();
        }
    }
    for (int t = tid; t < PRE_TOPN; t += 1024) {
        unsigned int idx = sidx[t];
        dboxes[(size_t)img * PRE_TOPN + t] = dprops[(size_t)img * NSC + idx];
    }
}

// ---------------- suppression bitmask (fp64 IoU): mask[i] bit j = IoU>0.7 && j>i
__global__ __launch_bounds__(256) void iou_mask_kernel(const double4* __restrict__ dboxes,
                                                       u64* __restrict__ mask) {
    const int tid = threadIdx.x;
    const int ib = blockIdx.x;
    const int img = blockIdx.y;
    const int i = ib * 64 + (tid >> 2);
    if (i >= PRE_TOPN) return;
    const double4 bi = dboxes[(size_t)img * PRE_TOPN + i];
    const double ai = (bi.z - bi.x) * (bi.w - bi.y);
    for (int w = (tid & 3); w < NWORDS; w += 4) {
        const int jbase = w * 64;
        u64 m = 0;
        if (jbase + 63 > i) {
            const int jmax = min(64, PRE_TOPN - jbase);
            for (int b = 0; b < jmax; ++b) {
                int j = jbase + b;
                if (j > i) {
                    double4 bj = dboxes[(size_t)img * PRE_TOPN + j];
                    double aj = (bj.z - bj.x) * (bj.w - bj.y);
                    double ltx = fmax(bi.x, bj.x), lty = fmax(bi.y, bj.y);
                    double rbx = fmin(bi.z, bj.z), rby = fmin(bi.w, bj.w);
                    double iw = fmax(rbx - ltx, 0.0), ih = fmax(rby - lty, 0.0);
                    double inter = iw * ih;
                    double iou = inter / (ai + aj - inter + 1e-9);
                    if (iou > 0.7) m |= (1ull << b);
                }
            }
        }
        mask[((size_t)img * PRE_TOPN + i) * MSTRIDE + w] = m;
    }
}

// ---------------- greedy walk (1 wave / image) + emit 300 boxes (zero-padded)
__global__ __launch_bounds__(64) void nms_walk(const double4* __restrict__ dboxes,
                                               const u64* __restrict__ mask,
                                               float4* __restrict__ outb) {
    const int img = blockIdx.x;
    const int lane = threadIdx.x;
    __shared__ u64 removed[NWORDS];
    __shared__ short kept[POST_TOPN];
    __shared__ int nk;
    if (lane < NWORDS) removed[lane] = 0ull;
    if (lane == 0) nk = 0;
    __syncthreads();
    for (int i = 0; i < PRE_TOPN; ++i) {
        u64 rw = removed[i >> 6];
        int cur = nk;
        if (!((rw >> (i & 63)) & 1ull)) {
            if (lane == 0) { kept[cur] = (short)i; nk = cur + 1; }
            if (cur + 1 >= POST_TOPN) break;
            if (lane < NWORDS)
                removed[lane] |= mask[((size_t)img * PRE_TOPN + i) * MSTRIDE + lane];
        }
        __syncthreads();
    }
    __syncthreads();
    const int n = nk;
    for (int r = lane; r < POST_TOPN; r += 64) {
        float4 v = make_float4(0.f, 0.f, 0.f, 0.f);
        if (r < n) {
            double4 d = dboxes[(size_t)img * PRE_TOPN + kept[r]];
            v = make_float4((float)d.x, (float)d.y, (float)d.z, (float)d.w);
        }
        outb[img * POST_TOPN + r] = v;
    }
}

extern "C" void kernel_launch(void* const* d_in, const int* in_sizes, int n_in,
                              void* d_out, int out_size, void* d_ws, size_t ws_size,
                              hipStream_t stream) {
    const float* x = (const float*)d_in[0];
    const float* im_size = (const float*)d_in[1];
    const float* Wconv = (const float*)d_in[2];
    const float* bconv = (const float*)d_in[3];
    const float* Wreg = (const float*)d_in[4];
    const float* breg = (const float*)d_in[5];
    const float* Wcls = (const float*)d_in[6];
    const float* bcls = (const float*)d_in[7];

    float* outf = (float*)d_out;
    float4* out_boxes = (float4*)outf;                               // 8*300*4
    float* out_scores = outf + NIMG * POST_TOPN * 4;                 // 8*36864
    float4* out_props = (float4*)(out_scores + (size_t)NIMG * NSC);  // 8*36864*4

    char* ws = (char*)d_ws;
    const size_t WT_OFF = 0;
    const size_t WH_OFF = WT_OFF + (size_t)4608 * 512 * 4;
    const size_t TS_OFF = WH_OFF + (size_t)512 * 64 * 4;
    const size_t DS_OFF = (TS_OFF + 8 * NIMG + 255) & ~(size_t)255;
    const size_t DP_OFF = DS_OFF + (size_t)NIMG * NSC * 8;
    const size_t DB_OFF = DP_OFF + (size_t)NIMG * NSC * 32;
    const size_t MK_OFF = DB_OFF + (size_t)NIMG * PRE_TOPN * 32;
    const size_t CV_OFF = (MK_OFF + (size_t)NIMG * PRE_TOPN * MSTRIDE * 8 + 255) & ~(size_t)255;

    float* Wt = (float*)(ws + WT_OFF);
    float* Wh = (float*)(ws + WH_OFF);
    u64* Tsel = (u64*)(ws + TS_OFF);
    double* dscores = (double*)(ws + DS_OFF);
    double4* dprops = (double4*)(ws + DP_OFF);
    double4* dboxes = (double4*)(ws + DB_OFF);
    u64* mask = (u64*)(ws + MK_OFF);
    double* convb = (double*)(ws + CV_OFF);

    const size_t per_img = (size_t)COUT * NPOS * 8;
    int CH = 1;
    if (ws_size > CV_OFF + per_img) {
        size_t avail = (ws_size - CV_OFF) / per_img;
        CH = (int)(avail > 8 ? 8 : avail);
        if (CH < 1) CH = 1;
    }

    transpose_wconv<<<dim3(144, 16), 256, 0, stream>>>(Wconv, Wt);
    build_wheads<<<128, 256, 0, stream>>>(Wreg, Wcls, Wh);

    for (int base = 0; base < NIMG; base += CH) {
        int n = NIMG - base;
        if (n > CH) n = CH;
        conv_kernel<<<dim3(8, 64, n), 256, 0, stream>>>(x, Wt, bconv, convb, base);
        heads_kernel<<<dim3(64, n), 256, 0, stream>>>(convb, Wh, breg, bcls, im_size,
                                                      out_scores, out_props,
                                                      dscores, dprops, base);
    }
    topk_select<<<NIMG, 256, 0, stream>>>(dscores, Tsel);
    sort_gather<<<NIMG, 1024, 0, stream>>>(dscores, dprops, Tsel, dboxes);
    iou_mask_kernel<<<dim3(NWORDS, NIMG), 256, 0, stream>>>(dboxes, mask);
    nms_walk<<<NIMG, 64, 0, stream>>>(dboxes, mask, out_boxes);
}